// Round 6
// baseline (299.652 us; speedup 1.0000x reference)
//
#include <hip/hip_runtime.h>
#include <hip/hip_bf16.h>

// OUTPUTS ARE FLOAT32 (reference returns jnp.float32; harness reads f32).
// Inputs are float32 (settled empirically: R4 runtime dtype vote).

// ---------------- Kernel A: P1 = b_in + nodes@W_in[0:256], P2 = nodes@W_in[256:512]
// nodes [1024,256] f32, W_in [768,256] f32 row-major. 8 node rows per block.
#define ROWS_A 8
__global__ __launch_bounds__(256) void k_precompute(
    const float* __restrict__ nodes, const float* __restrict__ W_in,
    const float* __restrict__ b_in, float* __restrict__ P1, float* __restrict__ P2)
{
  __shared__ float4 nd[ROWS_A][64];  // [row][k4]
  const int t = threadIdx.x;
  const int row0 = blockIdx.x * ROWS_A;
  const float4* np4 = (const float4*)(nodes + (size_t)row0 * 256);
#pragma unroll
  for (int q = 0; q < 2; q++){
    int idx = q * 256 + t;           // 512 float4 total
    nd[idx >> 6][idx & 63] = np4[idx];
  }
  __syncthreads();
  const int d = t;
  float acc1[ROWS_A], acc2[ROWS_A];
  float bin = b_in[d];
#pragma unroll
  for (int r = 0; r < ROWS_A; r++){ acc1[r] = bin; acc2[r] = 0.f; }
  for (int k4 = 0; k4 < 64; k4++){
    float w1[4], w2[4];
#pragma unroll
    for (int q = 0; q < 4; q++){
      int k = k4 * 4 + q;
      w1[q] = W_in[(size_t)k * 256 + d];
      w2[q] = W_in[(size_t)(256 + k) * 256 + d];
    }
#pragma unroll
    for (int r = 0; r < ROWS_A; r++){
      float4 n4 = nd[r][k4];
      acc1[r] += n4.x*w1[0] + n4.y*w1[1] + n4.z*w1[2] + n4.w*w1[3];
      acc2[r] += n4.x*w2[0] + n4.y*w2[1] + n4.z*w2[2] + n4.w*w2[3];
    }
  }
#pragma unroll
  for (int r = 0; r < ROWS_A; r++){
    P1[(size_t)(row0 + r) * 256 + d] = acc1[r];
    P2[(size_t)(row0 + r) * 256 + d] = acc2[r];
  }
}

// ---------------- Kernel B: one block per (b,i). Full fusion.
// h = relu(edge@W3 + P1[i] + P2[j]); coef = h@W_coef (+b_coef, cancels in
// softmax); softmax_j diag-masked; residual; new_nodes = nodes + relu(res@W_out + b_out)
__global__ __launch_bounds__(256) void k_main(
    const float* __restrict__ nodes, const float* __restrict__ edges,
    const float* __restrict__ W_in, const float* __restrict__ W_coef,
    const float* __restrict__ b_coef, const float* __restrict__ W_out,
    const float* __restrict__ b_out, const float* __restrict__ P1,
    const float* __restrict__ P2, float* __restrict__ out_nodes,
    float* __restrict__ out_h)
{
  __shared__ float elds[64 * 256];   // edges (f32), reused for h (f32)
  __shared__ float coefS[64];
  __shared__ float attnS[64];
  __shared__ float resS[256];

  const int t = threadIdx.x;
  const int bi = blockIdx.x;          // b*64 + i
  const int b = bi >> 6, i = bi & 63;

  // stage edge tile [64][256] f32 -> LDS (64 KB), 16 float4 per thread
  {
    const float4* ep = (const float4*)(edges + (size_t)bi * 64 * 256);
    float4* el4 = (float4*)elds;
#pragma unroll
    for (int q = 0; q < 16; q++){
      int e = q * 256 + t;
      el4[e] = ep[e];
    }
  }
  __syncthreads();

  const int cg = t & 31, rg = t >> 5;
  const int c0 = cg * 8, r0 = rg * 8;
  const float* W3 = W_in + (size_t)512 * 256;

  // GEMM: acc[rj][cj] = sum_k edge[r0+rj, k] * W3[k, c0+cj]
  float acc[8][8];
#pragma unroll
  for (int rj = 0; rj < 8; rj++)
#pragma unroll
    for (int cj = 0; cj < 8; cj++) acc[rj][cj] = 0.f;

  for (int k4 = 0; k4 < 64; k4++){
    float w_[4][8];
#pragma unroll
    for (int q = 0; q < 4; q++){
      const float* wr = W3 + (size_t)(k4 * 4 + q) * 256 + c0;
      float4 a = *(const float4*)wr;
      float4 bb = *(const float4*)(wr + 4);
      w_[q][0]=a.x;  w_[q][1]=a.y;  w_[q][2]=a.z;  w_[q][3]=a.w;
      w_[q][4]=bb.x; w_[q][5]=bb.y; w_[q][6]=bb.z; w_[q][7]=bb.w;
    }
#pragma unroll
    for (int rj = 0; rj < 8; rj++){
      float4 e4 = *(const float4*)&elds[(r0 + rj) * 256 + k4 * 4];  // wave-broadcast
#pragma unroll
      for (int cj = 0; cj < 8; cj++){
        acc[rj][cj] += e4.x*w_[0][cj] + e4.y*w_[1][cj] + e4.z*w_[2][cj] + e4.w*w_[3][cj];
      }
    }
  }
  __syncthreads();   // all edge reads done before overwriting elds with h

  // epilogue: h = relu(acc + P1[i,c] + P2[j,c]); write h (f32); coef partials
  float p1v[8], wcv[8];
  {
    const float4* p1p = (const float4*)(P1 + (size_t)bi * 256 + c0);
    float4 a = p1p[0], bb = p1p[1];
    p1v[0]=a.x;  p1v[1]=a.y;  p1v[2]=a.z;  p1v[3]=a.w;
    p1v[4]=bb.x; p1v[5]=bb.y; p1v[6]=bb.z; p1v[7]=bb.w;
    const float4* wcp = (const float4*)(W_coef + c0);
    float4 c = wcp[0], d4 = wcp[1];
    wcv[0]=c.x;  wcv[1]=c.y;  wcv[2]=c.z;  wcv[3]=c.w;
    wcv[4]=d4.x; wcv[5]=d4.y; wcv[6]=d4.z; wcv[7]=d4.w;
  }
  float pc[8];
#pragma unroll
  for (int rj = 0; rj < 8; rj++){
    const int row = r0 + rj;
    const int nrow = b * 64 + row;
    const float4* p2p = (const float4*)(P2 + (size_t)nrow * 256 + c0);
    float4 a = p2p[0], bb = p2p[1];
    float p2v[8] = {a.x,a.y,a.z,a.w,bb.x,bb.y,bb.z,bb.w};
    float h[8];
    float part = 0.f;
#pragma unroll
    for (int cj = 0; cj < 8; cj++){
      float v = acc[rj][cj] + p1v[cj] + p2v[cj];
      v = v > 0.f ? v : 0.f;
      h[cj] = v;
      part += v * wcv[cj];
    }
    pc[rj] = part;
    // h -> LDS (f32)
    *(float4*)&elds[row * 256 + c0]     = make_float4(h[0], h[1], h[2], h[3]);
    *(float4*)&elds[row * 256 + c0 + 4] = make_float4(h[4], h[5], h[6], h[7]);
    // h -> global as FLOAT32
    float* hp = out_h + ((size_t)bi * 64 + row) * 256 + c0;
    *(float4*)hp       = make_float4(h[0], h[1], h[2], h[3]);
    *(float4*)(hp + 4) = make_float4(h[4], h[5], h[6], h[7]);
  }

  // reduce pc over the 32 lanes sharing a row group (stays within half-wave)
#pragma unroll
  for (int rj = 0; rj < 8; rj++){
    float v = pc[rj];
#pragma unroll
    for (int off = 16; off >= 1; off >>= 1) v += __shfl_xor(v, off, 64);
    pc[rj] = v;
  }
  if (cg == 0){
#pragma unroll
    for (int rj = 0; rj < 8; rj++) coefS[r0 + rj] = pc[rj];
  }
  __syncthreads();

  // softmax over j (threads 0..63); b_coef shifts all coefs equally -> cancels
  if (t < 64){
    int j = t;
    float val = coefS[j] + b_coef[0] - (j == i ? 1e9f : 0.f);
    float m = val;
#pragma unroll
    for (int off = 32; off >= 1; off >>= 1){ float o = __shfl_xor(m, off, 64); m = m > o ? m : o; }
    float e = __expf(val - m);
    float s = e;
#pragma unroll
    for (int off = 32; off >= 1; off >>= 1) s += __shfl_xor(s, off, 64);
    attnS[j] = e / s;
  }
  __syncthreads();

  // residual[d] = sum_j attn[j] * h[j][d]
  {
    const int d = t;
    float res = 0.f;
#pragma unroll 8
    for (int j = 0; j < 64; j++) res += attnS[j] * elds[j * 256 + d];
    resS[d] = res;
  }
  __syncthreads();

  // new_nodes = nodes + relu(res @ W_out + b_out)  -> FLOAT32
  {
    const int d = t;
    float acco = b_out[d];
    for (int k4 = 0; k4 < 64; k4++){
      float4 r4 = *(const float4*)&resS[k4 * 4];
      acco += r4.x * W_out[(size_t)(k4*4 + 0) * 256 + d];
      acco += r4.y * W_out[(size_t)(k4*4 + 1) * 256 + d];
      acco += r4.z * W_out[(size_t)(k4*4 + 2) * 256 + d];
      acco += r4.w * W_out[(size_t)(k4*4 + 3) * 256 + d];
    }
    float nv = nodes[(size_t)bi * 256 + d];
    out_nodes[(size_t)bi * 256 + d] = nv + (acco > 0.f ? acco : 0.f);
  }
}

extern "C" void kernel_launch(void* const* d_in, const int* in_sizes, int n_in,
                              void* d_out, int out_size, void* d_ws, size_t ws_size,
                              hipStream_t stream)
{
  const float* nodes  = (const float*)d_in[0];
  const float* edges  = (const float*)d_in[1];
  const float* W_in   = (const float*)d_in[2];
  const float* b_in   = (const float*)d_in[3];
  const float* W_coef = (const float*)d_in[4];
  const float* b_coef = (const float*)d_in[5];
  const float* W_out  = (const float*)d_in[6];
  const float* b_out  = (const float*)d_in[7];
  (void)in_sizes; (void)n_in; (void)out_size; (void)ws_size;

  float* P1 = (float*)d_ws;            // [1024][256] f32 (ws proven good: R2==R3)
  float* P2 = P1 + 1024 * 256;         // [1024][256] f32

  float* out_nodes = (float*)d_out;          // [1024*256] f32
  float* out_h = out_nodes + 1024 * 256;     // [65536*256] f32

  hipLaunchKernelGGL(k_precompute, dim3(128), dim3(256), 0, stream,
                     nodes, W_in, b_in, P1, P2);
  hipLaunchKernelGGL(k_main, dim3(1024), dim3(256), 0, stream,
                     nodes, edges, W_in, W_coef, b_coef, W_out, b_out,
                     P1, P2, out_nodes, out_h);
}

// Round 7
// 183.785 us; speedup vs baseline: 1.6305x; 1.6305x over previous
//
#include <hip/hip_runtime.h>
#include <hip/hip_bf16.h>

typedef unsigned int u32;
typedef unsigned short u16;
typedef __attribute__((ext_vector_type(8))) short bf16x8;   // 8 bf16 in 4 VGPRs
typedef __attribute__((ext_vector_type(4))) float f32x4;

#define DI __device__ __forceinline__

DI u16 f2bfu(float f){
  union{float f; u32 i;} u; u.f = f;
  u32 lsb = (u.i >> 16) & 1u;
  u.i += 0x7fffu + lsb;    // RNE
  return (u16)(u.i >> 16);
}

union BU { uint4 v; bf16x8 s; };

// ---------------- pack W_in into MFMA B-fragment order (bf16) ----------------
// B-frag for 16x16x32: lane l holds B[k = (l>>4)*8 + t][n = l&15], t=0..7.
// Wp3 : [nt 16][kk 8][lane 64][t 8]  <- W3  = W_in[512 + k][n]   (k=kk*32+...)
// Wp12: [half 2][nt 16][kk 8][lane 64][t 8] <- W_in[half*256 + k][n]
__global__ __launch_bounds__(256) void k_pack(const float* __restrict__ W_in,
                                              u16* __restrict__ Wp3,
                                              u16* __restrict__ Wp12)
{
  int idx = blockIdx.x * 256 + threadIdx.x;   // [0, 24576)
  int l = idx & 63;
  int g = idx >> 6;                            // [0, 384)
  int lq = l >> 4, lr = l & 15;
  u16 o[8];
  if (g < 128){            // W3: g = nt*8 + kk
    int nt = g >> 3, kk = g & 7;
    int n  = nt * 16 + lr;
    int k0 = 512 + kk * 32 + lq * 8;
#pragma unroll
    for (int tt = 0; tt < 8; tt++) o[tt] = f2bfu(W_in[(size_t)(k0 + tt) * 256 + n]);
    *(uint4*)(Wp3 + (size_t)idx * 8) = *(uint4*)o;
  } else {                 // W12: (g-128) = half*128 + nt*8 + kk
    int g2 = g - 128;
    int half = g2 >> 7, rem = g2 & 127;
    int nt = rem >> 3, kk = rem & 7;
    int n  = nt * 16 + lr;
    int k0 = half * 256 + kk * 32 + lq * 8;
#pragma unroll
    for (int tt = 0; tt < 8; tt++) o[tt] = f2bfu(W_in[(size_t)(k0 + tt) * 256 + n]);
    *(uint4*)(Wp12 + (size_t)g2 * 512 + (size_t)l * 8) = *(uint4*)o;
  }
}

// ---------------- k_pre: P1 = b_in + nodes@W1, P2 = nodes@W2 (bf16 MFMA) ----
// 32 blocks: rt = bid>>1 (64-row tile), half = bid&1 (P1 or P2).
__global__ __launch_bounds__(256) void k_pre(
    const float* __restrict__ nodes, const float* __restrict__ b_in,
    const u16* __restrict__ Wp12, float* __restrict__ P1, float* __restrict__ P2)
{
  const int t = threadIdx.x;
  const int w = t >> 6, l = t & 63, lq = l >> 4, lr = l & 15;
  const int rt = blockIdx.x >> 1, half = blockIdx.x & 1;

  // A-frags: nodes[row = rt*64 + 16w + lr][k = kk*32 + lq*8 + t]
  bf16x8 af[8];
  {
    const float* ap = nodes + (size_t)(rt * 64 + 16 * w + lr) * 256 + lq * 8;
#pragma unroll
    for (int kk = 0; kk < 8; kk++){
      float4 x = *(const float4*)(ap + kk * 32);
      float4 y = *(const float4*)(ap + kk * 32 + 4);
      bf16x8 a;
      a[0]=(short)f2bfu(x.x); a[1]=(short)f2bfu(x.y); a[2]=(short)f2bfu(x.z); a[3]=(short)f2bfu(x.w);
      a[4]=(short)f2bfu(y.x); a[5]=(short)f2bfu(y.y); a[6]=(short)f2bfu(y.z); a[7]=(short)f2bfu(y.w);
      af[kk] = a;
    }
  }
  const uint4* wp = (const uint4*)(Wp12 + (size_t)half * 128 * 512);
  float* P = half ? P2 : P1;
#pragma unroll
  for (int nt = 0; nt < 16; nt++){
    f32x4 acc = {0.f, 0.f, 0.f, 0.f};
#pragma unroll
    for (int kk = 0; kk < 8; kk++){
      BU bu; bu.v = wp[(nt * 8 + kk) * 64 + l];
      acc = __builtin_amdgcn_mfma_f32_16x16x32_bf16(af[kk], bu.s, acc, 0, 0, 0);
    }
    const int col = nt * 16 + lr;
    const float bv = half ? 0.f : b_in[col];
#pragma unroll
    for (int r = 0; r < 4; r++){
      const int row = rt * 64 + 16 * w + 4 * lq + r;   // C/D: row = quad*4+reg
      P[(size_t)row * 256 + col] = acc[r] + bv;
    }
  }
}

// ---------------- k_main: one block per (b,i), bf16 MFMA + fused epilogue ---
__global__ __launch_bounds__(256) void k_main(
    const float* __restrict__ nodes, const float* __restrict__ edges,
    const u16* __restrict__ Wp3, const float* __restrict__ W_coef,
    const float* __restrict__ b_coef, const float* __restrict__ W_out,
    const float* __restrict__ b_out, const float* __restrict__ P1,
    const float* __restrict__ P2, float* __restrict__ out_nodes,
    float* __restrict__ out_h)
{
  __shared__ float hS[64 * 256];    // h (f32) for residual stage
  __shared__ float coefS[64];
  __shared__ float attnS[64];
  __shared__ float resS[256];

  const int t = threadIdx.x;
  const int w = t >> 6, l = t & 63, lq = l >> 4, lr = l & 15;
  const int bi = blockIdx.x;          // b*64 + i
  const int b = bi >> 6, i = bi & 63;

  // A-frags: edge rows (j = 16w + lr), f32 -> bf16 in flight
  bf16x8 af[8];
  {
    const float* ap = edges + (size_t)bi * 16384 + (size_t)(16 * w + lr) * 256 + lq * 8;
#pragma unroll
    for (int kk = 0; kk < 8; kk++){
      float4 x = *(const float4*)(ap + kk * 32);
      float4 y = *(const float4*)(ap + kk * 32 + 4);
      bf16x8 a;
      a[0]=(short)f2bfu(x.x); a[1]=(short)f2bfu(x.y); a[2]=(short)f2bfu(x.z); a[3]=(short)f2bfu(x.w);
      a[4]=(short)f2bfu(y.x); a[5]=(short)f2bfu(y.y); a[6]=(short)f2bfu(y.z); a[7]=(short)f2bfu(y.w);
      af[kk] = a;
    }
  }

  const uint4* wp = (const uint4*)Wp3;
  float cpart[4] = {0.f, 0.f, 0.f, 0.f};
#pragma unroll
  for (int nt = 0; nt < 16; nt++){
    f32x4 acc = {0.f, 0.f, 0.f, 0.f};
#pragma unroll
    for (int kk = 0; kk < 8; kk++){
      BU bu; bu.v = wp[(nt * 8 + kk) * 64 + l];
      acc = __builtin_amdgcn_mfma_f32_16x16x32_bf16(af[kk], bu.s, acc, 0, 0, 0);
    }
    const int col = nt * 16 + lr;
    const float p1 = P1[(size_t)bi * 256 + col];
    const float wc = W_coef[col];
#pragma unroll
    for (int r = 0; r < 4; r++){
      const int row = 16 * w + 4 * lq + r;             // local j
      const float p2 = P2[((size_t)b * 64 + row) * 256 + col];
      float h = acc[r] + p1 + p2;
      h = h > 0.f ? h : 0.f;
      hS[row * 256 + col] = h;
      out_h[((size_t)bi * 64 + row) * 256 + col] = h;  // f32 output
      cpart[r] += h * wc;
    }
  }

  // coef: reduce cpart over the 16 lanes of each quad (cols lr=0..15 mod 16)
#pragma unroll
  for (int r = 0; r < 4; r++){
    float v = cpart[r];
    v += __shfl_xor(v, 1, 64);
    v += __shfl_xor(v, 2, 64);
    v += __shfl_xor(v, 4, 64);
    v += __shfl_xor(v, 8, 64);
    if (lr == 0) coefS[16 * w + 4 * lq + r] = v;
  }
  __syncthreads();

  // softmax over j (threads 0..63); b_coef shifts all coefs equally
  if (t < 64){
    int j = t;
    float val = coefS[j] + b_coef[0] - (j == i ? 1e9f : 0.f);
    float m = val;
#pragma unroll
    for (int off = 32; off >= 1; off >>= 1){ float o = __shfl_xor(m, off, 64); m = m > o ? m : o; }
    float e = __expf(val - m);
    float s = e;
#pragma unroll
    for (int off = 32; off >= 1; off >>= 1) s += __shfl_xor(s, off, 64);
    attnS[j] = e / s;
  }
  __syncthreads();

  // residual[d] = sum_j attn[j] * h[j][d]
  {
    const int d = t;
    float res = 0.f;
#pragma unroll 8
    for (int j = 0; j < 64; j++) res += attnS[j] * hS[j * 256 + d];
    resS[d] = res;
  }
  __syncthreads();

  // new_nodes = nodes + relu(res @ W_out + b_out)  (f32)
  {
    const int d = t;
    float acco = b_out[d];
    for (int k4 = 0; k4 < 64; k4++){
      float4 r4 = *(const float4*)&resS[k4 * 4];
      acco += r4.x * W_out[(size_t)(k4 * 4 + 0) * 256 + d];
      acco += r4.y * W_out[(size_t)(k4 * 4 + 1) * 256 + d];
      acco += r4.z * W_out[(size_t)(k4 * 4 + 2) * 256 + d];
      acco += r4.w * W_out[(size_t)(k4 * 4 + 3) * 256 + d];
    }
    float nv = nodes[(size_t)bi * 256 + d];
    out_nodes[(size_t)bi * 256 + d] = nv + (acco > 0.f ? acco : 0.f);
  }
}

extern "C" void kernel_launch(void* const* d_in, const int* in_sizes, int n_in,
                              void* d_out, int out_size, void* d_ws, size_t ws_size,
                              hipStream_t stream)
{
  const float* nodes  = (const float*)d_in[0];
  const float* edges  = (const float*)d_in[1];
  const float* W_in   = (const float*)d_in[2];
  const float* b_in   = (const float*)d_in[3];
  const float* W_coef = (const float*)d_in[4];
  const float* b_coef = (const float*)d_in[5];
  const float* W_out  = (const float*)d_in[6];
  const float* b_out  = (const float*)d_in[7];
  (void)in_sizes; (void)n_in; (void)out_size; (void)ws_size;

  float* P1  = (float*)d_ws;           // [1024][256] f32
  float* P2  = P1 + 262144;            // [1024][256] f32
  u16*  Wp3  = (u16*)(P2 + 262144);    // 65536 bf16 (128 KB)
  u16*  Wp12 = Wp3 + 65536;            // 131072 bf16 (256 KB)

  float* out_nodes = (float*)d_out;          // [1024*256] f32
  float* out_h = out_nodes + 262144;         // [65536*256] f32

  hipLaunchKernelGGL(k_pack, dim3(96),   dim3(256), 0, stream, W_in, Wp3, Wp12);
  hipLaunchKernelGGL(k_pre,  dim3(32),   dim3(256), 0, stream, nodes, b_in, Wp12, P1, P2);
  hipLaunchKernelGGL(k_main, dim3(1024), dim3(256), 0, stream,
                     nodes, edges, Wp3, W_coef, b_coef, W_out, b_out,
                     P1, P2, out_nodes, out_h);
}